// Round 8
// baseline (126.233 us; speedup 1.0000x reference)
//
#include <hip/hip_runtime.h>

// Hierarchical softmax: B=4096, NHID=512, BR=32, DEPTH=3, V=32768.
// bucket g = lab>>5. node0=0 (step g>>5), node1=1+(g>>5) (step g&31),
// node2=33+g (step lab&31). out[b] = prod_k softmax(x_b @ W[node_k])[step_k]
//
// R8: R7's proven shape (192 thr, wave k = level k, one uninterrupted
// 64-iteration coalesced float4 W-stream per wave) with SMAX=8: group count
// ~1480 -> ~660, logical W traffic ~284 MB -> ~127 MB through the measured
// ~24 B/cyc/CU L1-miss issue wall. Sort scan rewritten as two-level shuffle
// scan (2 barriers instead of 20).

#define NHID  512
#define BR    32
#define BATCH 4096
#define NBUCK 1024
#define SMAX  8
#define GMAX  1536   // worst case: 4096/8 + 1024 partial = 1536

#define FMA4(A, xv, wv_) do { \
    (A).x = fmaf((xv), (wv_).x, (A).x); \
    (A).y = fmaf((xv), (wv_).y, (A).y); \
    (A).z = fmaf((xv), (wv_).z, (A).z); \
    (A).w = fmaf((xv), (wv_).w, (A).w); } while (0)

// ---------- single-block counting sort + ordered group descriptors ----------
__global__ __launch_bounds__(1024) void k_sort(const int* __restrict__ labels,
                                               int* __restrict__ order,
                                               int* __restrict__ ngroups,
                                               int* __restrict__ gdesc) {
    __shared__ int labs[BATCH];    // 16 KB
    __shared__ int hist[NBUCK];    // 4 KB (count -> cursor)
    __shared__ int wsum1[16];      // wave totals (samples)
    __shared__ int wsum2[16];      // wave totals (groups)
    const int t  = threadIdx.x;
    const int wv = t >> 6;
    const int ln = t & 63;

    hist[t] = 0;
    #pragma unroll
    for (int r = 0; r < BATCH / 1024; ++r)
        labs[t + 1024 * r] = labels[t + 1024 * r];
    __syncthreads();
    #pragma unroll
    for (int r = 0; r < BATCH / 1024; ++r)
        atomicAdd(&hist[labs[t + 1024 * r] >> 5], 1);
    __syncthreads();

    const int cnt  = hist[t];
    const int gcnt = (cnt + SMAX - 1) / SMAX;

    // two-level inclusive scan of (cnt, gcnt) over 1024 threads
    int s1 = cnt, s2 = gcnt;
    #pragma unroll
    for (int d = 1; d < 64; d <<= 1) {
        int u1 = __shfl_up(s1, d);
        int u2 = __shfl_up(s2, d);
        if (ln >= d) { s1 += u1; s2 += u2; }
    }
    if (ln == 63) { wsum1[wv] = s1; wsum2[wv] = s2; }
    __syncthreads();
    if (t < 16) {
        int a = wsum1[t], b = wsum2[t];
        #pragma unroll
        for (int d = 1; d < 16; d <<= 1) {
            int ua = __shfl_up(a, d, 16);
            int ub = __shfl_up(b, d, 16);
            if (t >= d) { a += ua; b += ub; }
        }
        wsum1[t] = a; wsum2[t] = b;
        if (t == 15) *ngroups = b;
    }
    __syncthreads();
    const int base1 = (wv > 0) ? wsum1[wv - 1] : 0;
    const int base2 = (wv > 0) ? wsum2[wv - 1] : 0;
    const int off  = base1 + s1 - cnt;    // exclusive sample offset
    const int goff = base2 + s2 - gcnt;   // exclusive group offset
    hist[t] = off;                        // becomes scatter cursor
    __syncthreads();

    // ordered descriptors: (start | m<<12 | bucket<<16)
    for (int j = 0; j < gcnt; ++j)
        gdesc[goff + j] = (off + j * SMAX)
                        | (min(SMAX, cnt - j * SMAX) << 12)
                        | (t << 16);

    #pragma unroll
    for (int r = 0; r < BATCH / 1024; ++r) {
        int j = t + 1024 * r;
        int pos = atomicAdd(&hist[labs[j] >> 5], 1);
        order[pos] = j;
    }
}

// ---------- compute: one block per group of 8, wave k = level k ----------
__global__ __launch_bounds__(192) void hsm_g8(
    const float* __restrict__ inputs,
    const int* __restrict__ labels,
    const float* __restrict__ W,
    const int* __restrict__ order,
    const int* __restrict__ ngroups,
    const int* __restrict__ gdesc,
    float* __restrict__ out)
{
    __shared__ float xsT[NHID * SMAX];   // 16 KB, xsT[h][s0..7]
    __shared__ float pk[3][SMAX];
    __shared__ int   sids[SMAX];
    __shared__ int   slab[SMAX];

    const int gid = blockIdx.x;
    if (gid >= *ngroups) return;
    const int d     = gdesc[gid];
    const int start = d & 0xFFF;
    const int m     = (d >> 12) & 0xF;
    const int g     = d >> 16;
    const int tid   = threadIdx.x;

    if (tid < SMAX) {
        int sid = (tid < m) ? order[start + tid] : -1;
        sids[tid] = sid;
        slab[tid] = (sid >= 0) ? labels[sid] : 0;
    }
    __syncthreads();

    // ---- stage xsT[h][0..7] (32 B rows), zero-pad unused slots ----
    for (int h = tid; h < NHID; h += 192) {
        float v[SMAX];
        #pragma unroll
        for (int s = 0; s < SMAX; ++s) {
            int id = sids[s];
            v[s] = (id >= 0) ? inputs[(size_t)id * NHID + h] : 0.0f;
        }
        float4* dst = (float4*)&xsT[h * SMAX];
        dst[0] = make_float4(v[0], v[1], v[2], v[3]);
        dst[1] = make_float4(v[4], v[5], v[6], v[7]);
    }
    __syncthreads();

    const int k    = tid >> 6;    // wave = tree level
    const int lane = tid & 63;
    const int colg = lane & 7;    // float4 column group
    const int hsel = lane >> 3;   // h strip: h = 8i + hsel

    const int node = (k == 0) ? 0 : (k == 1) ? 1 + (g >> 5) : 33 + g;
    const int step01 = (k == 0) ? (g >> 5) : (g & 31);

    const float4* wp = (const float4*)(W + (size_t)node * (NHID * BR))
                       + hsel * 8 + colg;
    const float4* xp = (const float4*)xsT + hsel * 2;  // float4 idx = 2h

    float4 acc[SMAX];
    #pragma unroll
    for (int s = 0; s < SMAX; ++s) acc[s] = make_float4(0, 0, 0, 0);

    // one uninterrupted coalesced stream: 64 x (1 KB/wave) loads
    #pragma unroll 8
    for (int i = 0; i < 64; ++i) {
        float4 w  = wp[i * 64];       // row 8i+hsel, cols 4*colg..
        float4 xa = xp[i * 16];       // xsT[8i+hsel][0..3] (broadcast)
        float4 xb = xp[i * 16 + 1];   // xsT[8i+hsel][4..7]
        FMA4(acc[0], xa.x, w); FMA4(acc[1], xa.y, w);
        FMA4(acc[2], xa.z, w); FMA4(acc[3], xa.w, w);
        FMA4(acc[4], xb.x, w); FMA4(acc[5], xb.y, w);
        FMA4(acc[6], xb.z, w); FMA4(acc[7], xb.w, w);
    }

    // butterfly-reduce over hsel (masks 8,16,32): all lanes get full sums
    #pragma unroll
    for (int s = 0; s < SMAX; ++s) {
        #pragma unroll
        for (int mm = 8; mm <= 32; mm <<= 1) {
            acc[s].x += __shfl_xor(acc[s].x, mm);
            acc[s].y += __shfl_xor(acc[s].y, mm);
            acc[s].z += __shfl_xor(acc[s].z, mm);
            acc[s].w += __shfl_xor(acc[s].w, mm);
        }
    }

    // per-sample softmax over 32 logits (8 colg lanes x 4 comps)
    #pragma unroll
    for (int s = 0; s < SMAX; ++s) {
        float4 a = acc[s];
        float mx = fmaxf(fmaxf(a.x, a.y), fmaxf(a.z, a.w));
        #pragma unroll
        for (int mm = 1; mm <= 4; mm <<= 1) mx = fmaxf(mx, __shfl_xor(mx, mm));
        float es = expf(a.x - mx) + expf(a.y - mx) + expf(a.z - mx) + expf(a.w - mx);
        #pragma unroll
        for (int mm = 1; mm <= 4; mm <<= 1) es += __shfl_xor(es, mm);

        int step = (k == 2) ? (slab[s] & 31) : step01;
        int e = step & 3;
        float v = (e == 0) ? a.x : (e == 1) ? a.y : (e == 2) ? a.z : a.w;
        float sl = __shfl(v, step >> 2);
        float p = expf(sl - mx) / es;
        if (lane == 0) pk[k][s] = p;
    }
    __syncthreads();

    if (tid < SMAX && sids[tid] >= 0)
        out[sids[tid]] = pk[0][tid] * pk[1][tid] * pk[2][tid];
}

extern "C" void kernel_launch(void* const* d_in, const int* in_sizes, int n_in,
                              void* d_out, int out_size, void* d_ws, size_t ws_size,
                              hipStream_t stream)
{
    const float* inputs = (const float*)d_in[0];
    const int*   labels = (const int*)d_in[1];
    const float* W      = (const float*)d_in[2];
    float* out = (float*)d_out;

    char* ws = (char*)d_ws;
    int* order   = (int*)ws;                  // 16 KB
    int* ngroups = (int*)(ws + 16384);        // 4 B (padded to 128)
    int* gdesc   = (int*)(ws + 16384 + 128);  // 6 KB

    k_sort<<<dim3(1),    dim3(1024), 0, stream>>>(labels, order, ngroups, gdesc);
    hsm_g8<<<dim3(GMAX), dim3(192),  0, stream>>>(inputs, labels, W, order,
                                                  ngroups, gdesc, out);
}

// Round 9
// 122.087 us; speedup vs baseline: 1.0340x; 1.0340x over previous
//
#include <hip/hip_runtime.h>

// Hierarchical softmax: B=4096, NHID=512, BR=32, DEPTH=3, V=32768.
// bucket g = lab>>5. node0=0 (step g>>5), node1=1+(g>>5) (step g&31),
// node2=33+g (step lab&31). out[b] = prod_k softmax(x_b @ W[node_k])[step_k]
//
// R9: R8 structure (sort -> ~660 node2-uniform groups of 8; 192-thread
// blocks, wave k = level k) + explicit double-buffered register prefetch of
// the W stream. R1..R8 were all bound by ONE outstanding 1 KB load per wave
// (VGPR_Count 32-44 proves the compiler serialized: ~1.6 GB/s/wave). wcur[8]
// /wnxt[8] float4 arrays force 8-16 loads in flight -> per-wave rate ~x8-16,
// shifting the kernel to the real HBM/L2 walls.

#define NHID  512
#define BR    32
#define BATCH 4096
#define NBUCK 1024
#define SMAX  8
#define GMAX  1536   // worst case: 4096/8 + 1024 partial

#define FMA4(A, xv, wv_) do { \
    (A).x = fmaf((xv), (wv_).x, (A).x); \
    (A).y = fmaf((xv), (wv_).y, (A).y); \
    (A).z = fmaf((xv), (wv_).z, (A).z); \
    (A).w = fmaf((xv), (wv_).w, (A).w); } while (0)

// ---------- single-block counting sort + ordered group descriptors ----------
__global__ __launch_bounds__(1024) void k_sort(const int* __restrict__ labels,
                                               int* __restrict__ order,
                                               int* __restrict__ ngroups,
                                               int* __restrict__ gdesc) {
    __shared__ int labs[BATCH];    // 16 KB
    __shared__ int hist[NBUCK];    // 4 KB (count -> cursor)
    __shared__ int wsum1[16];
    __shared__ int wsum2[16];
    const int t  = threadIdx.x;
    const int wv = t >> 6;
    const int ln = t & 63;

    hist[t] = 0;
    #pragma unroll
    for (int r = 0; r < BATCH / 1024; ++r)
        labs[t + 1024 * r] = labels[t + 1024 * r];
    __syncthreads();
    #pragma unroll
    for (int r = 0; r < BATCH / 1024; ++r)
        atomicAdd(&hist[labs[t + 1024 * r] >> 5], 1);
    __syncthreads();

    const int cnt  = hist[t];
    const int gcnt = (cnt + SMAX - 1) / SMAX;

    int s1 = cnt, s2 = gcnt;
    #pragma unroll
    for (int d = 1; d < 64; d <<= 1) {
        int u1 = __shfl_up(s1, d);
        int u2 = __shfl_up(s2, d);
        if (ln >= d) { s1 += u1; s2 += u2; }
    }
    if (ln == 63) { wsum1[wv] = s1; wsum2[wv] = s2; }
    __syncthreads();
    if (t < 16) {
        int a = wsum1[t], b = wsum2[t];
        #pragma unroll
        for (int d = 1; d < 16; d <<= 1) {
            int ua = __shfl_up(a, d, 16);
            int ub = __shfl_up(b, d, 16);
            if (t >= d) { a += ua; b += ub; }
        }
        wsum1[t] = a; wsum2[t] = b;
        if (t == 15) *ngroups = b;
    }
    __syncthreads();
    const int base1 = (wv > 0) ? wsum1[wv - 1] : 0;
    const int base2 = (wv > 0) ? wsum2[wv - 1] : 0;
    const int off  = base1 + s1 - cnt;
    const int goff = base2 + s2 - gcnt;
    hist[t] = off;
    __syncthreads();

    for (int j = 0; j < gcnt; ++j)
        gdesc[goff + j] = (off + j * SMAX)
                        | (min(SMAX, cnt - j * SMAX) << 12)
                        | (t << 16);

    #pragma unroll
    for (int r = 0; r < BATCH / 1024; ++r) {
        int j = t + 1024 * r;
        int pos = atomicAdd(&hist[labs[j] >> 5], 1);
        order[pos] = j;
    }
}

// ---------- compute: one block per group of 8, wave k = level k ----------
__global__ __launch_bounds__(192) void hsm_g8(
    const float* __restrict__ inputs,
    const int* __restrict__ labels,
    const float* __restrict__ W,
    const int* __restrict__ order,
    const int* __restrict__ ngroups,
    const int* __restrict__ gdesc,
    float* __restrict__ out)
{
    __shared__ float xsT[NHID * SMAX];   // 16 KB, xsT[h][s0..7]
    __shared__ float pk[3][SMAX];
    __shared__ int   sids[SMAX];
    __shared__ int   slab[SMAX];

    const int gid = blockIdx.x;
    if (gid >= *ngroups) return;
    const int d     = gdesc[gid];
    const int start = d & 0xFFF;
    const int m     = (d >> 12) & 0xF;
    const int g     = d >> 16;
    const int tid   = threadIdx.x;

    if (tid < SMAX) {
        int sid = (tid < m) ? order[start + tid] : -1;
        sids[tid] = sid;
        slab[tid] = (sid >= 0) ? labels[sid] : 0;
    }
    __syncthreads();

    // ---- stage xsT[h][0..7] (32 B rows), zero-pad unused slots ----
    for (int h = tid; h < NHID; h += 192) {
        float v[SMAX];
        #pragma unroll
        for (int s = 0; s < SMAX; ++s) {
            int id = sids[s];
            v[s] = (id >= 0) ? inputs[(size_t)id * NHID + h] : 0.0f;
        }
        float4* dst = (float4*)&xsT[h * SMAX];
        dst[0] = make_float4(v[0], v[1], v[2], v[3]);
        dst[1] = make_float4(v[4], v[5], v[6], v[7]);
    }
    __syncthreads();

    const int k    = tid >> 6;    // wave = tree level
    const int lane = tid & 63;
    const int colg = lane & 7;    // float4 column group
    const int hsel = lane >> 3;   // h strip: h = 8i + hsel

    const int node = (k == 0) ? 0 : (k == 1) ? 1 + (g >> 5) : 33 + g;
    const int step01 = (k == 0) ? (g >> 5) : (g & 31);

    const float4* wp = (const float4*)(W + (size_t)node * (NHID * BR))
                       + hsel * 8 + colg;
    const float4* xp = (const float4*)xsT + hsel * 2;  // float4 idx = 2h

    float4 acc[SMAX];
    #pragma unroll
    for (int s = 0; s < SMAX; ++s) acc[s] = make_float4(0, 0, 0, 0);

    // ---- W stream with explicit double-buffered register prefetch ----
    // 8 loads in flight from wnxt while wcur's FMAs retire: 8-16 outstanding.
    float4 wcur[8], wnxt[8];
    #pragma unroll
    for (int j = 0; j < 8; ++j) wcur[j] = wp[j * 64];

    #pragma unroll
    for (int ii = 0; ii < 64; ii += 8) {
        if (ii + 8 < 64) {
            #pragma unroll
            for (int j = 0; j < 8; ++j) wnxt[j] = wp[(ii + 8 + j) * 64];
        }
        #pragma unroll
        for (int j = 0; j < 8; ++j) {
            float4 xa = xp[(ii + j) * 16];
            float4 xb = xp[(ii + j) * 16 + 1];
            FMA4(acc[0], xa.x, wcur[j]); FMA4(acc[1], xa.y, wcur[j]);
            FMA4(acc[2], xa.z, wcur[j]); FMA4(acc[3], xa.w, wcur[j]);
            FMA4(acc[4], xb.x, wcur[j]); FMA4(acc[5], xb.y, wcur[j]);
            FMA4(acc[6], xb.z, wcur[j]); FMA4(acc[7], xb.w, wcur[j]);
        }
        #pragma unroll
        for (int j = 0; j < 8; ++j) wcur[j] = wnxt[j];
    }

    // butterfly-reduce over hsel (masks 8,16,32): all lanes get full sums
    #pragma unroll
    for (int s = 0; s < SMAX; ++s) {
        #pragma unroll
        for (int mm = 8; mm <= 32; mm <<= 1) {
            acc[s].x += __shfl_xor(acc[s].x, mm);
            acc[s].y += __shfl_xor(acc[s].y, mm);
            acc[s].z += __shfl_xor(acc[s].z, mm);
            acc[s].w += __shfl_xor(acc[s].w, mm);
        }
    }

    // per-sample softmax over 32 logits (8 colg lanes x 4 comps)
    #pragma unroll
    for (int s = 0; s < SMAX; ++s) {
        float4 a = acc[s];
        float mx = fmaxf(fmaxf(a.x, a.y), fmaxf(a.z, a.w));
        #pragma unroll
        for (int mm = 1; mm <= 4; mm <<= 1) mx = fmaxf(mx, __shfl_xor(mx, mm));
        float es = expf(a.x - mx) + expf(a.y - mx) + expf(a.z - mx) + expf(a.w - mx);
        #pragma unroll
        for (int mm = 1; mm <= 4; mm <<= 1) es += __shfl_xor(es, mm);

        int step = (k == 2) ? (slab[s] & 31) : step01;
        int e = step & 3;
        float v = (e == 0) ? a.x : (e == 1) ? a.y : (e == 2) ? a.z : a.w;
        float sl = __shfl(v, step >> 2);
        float p = expf(sl - mx) / es;
        if (lane == 0) pk[k][s] = p;
    }
    __syncthreads();

    if (tid < SMAX && sids[tid] >= 0)
        out[sids[tid]] = pk[0][tid] * pk[1][tid] * pk[2][tid];
}

extern "C" void kernel_launch(void* const* d_in, const int* in_sizes, int n_in,
                              void* d_out, int out_size, void* d_ws, size_t ws_size,
                              hipStream_t stream)
{
    const float* inputs = (const float*)d_in[0];
    const int*   labels = (const int*)d_in[1];
    const float* W      = (const float*)d_in[2];
    float* out = (float*)d_out;

    char* ws = (char*)d_ws;
    int* order   = (int*)ws;                  // 16 KB
    int* ngroups = (int*)(ws + 16384);        // 4 B (padded to 128)
    int* gdesc   = (int*)(ws + 16384 + 128);  // 6 KB

    k_sort<<<dim3(1),    dim3(1024), 0, stream>>>(labels, order, ngroups, gdesc);
    hsm_g8<<<dim3(GMAX), dim3(192),  0, stream>>>(inputs, labels, W, order,
                                                  ngroups, gdesc, out);
}